// Round 1
// baseline (608.115 us; speedup 1.0000x reference)
//
#include <hip/hip_runtime.h>
#include <math.h>

// Problem constants
#define B_   8
#define T_   2048
#define V_   1024
#define C_   128
#define NB2  64     // 2*NB
#define L_   32     // chunk length for the linearized recurrence
#define NC_  64     // T_/L_

__device__ __forceinline__ float sigmoidf_(float x){ return 1.0f/(1.0f+expf(-x)); }

// ---------------------------------------------------------------------------
// K0: W[proj][v][c];  proj 0..2: softmax(basis@coeffs^T, axis=V); proj 3: raw
// grid: 4*128 blocks (proj,c), 256 threads
// ---------------------------------------------------------------------------
__global__ __launch_bounds__(256) void weights_kernel(
    const float* __restrict__ basis,
    const float* __restrict__ qc, const float* __restrict__ kc,
    const float* __restrict__ vc, const float* __restrict__ oc,
    float* __restrict__ W)
{
  int blk  = blockIdx.x;
  int proj = blk >> 7;
  int c    = blk & 127;
  const float* coeffs = (proj==0)?qc : (proj==1)?kc : (proj==2)?vc : oc;
  float* Wp = W + (size_t)proj * V_ * C_;

  __shared__ float coef[NB2];
  __shared__ float red[256];
  int tid = threadIdx.x;
  if (tid < NB2) coef[tid] = coeffs[c*NB2 + tid];
  __syncthreads();

  float l[4];
  for (int i=0;i<4;i++){
    int v = tid + i*256;
    const float4* bp = (const float4*)(basis + (size_t)v*NB2);
    float s = 0.f;
    #pragma unroll
    for (int f=0; f<NB2/4; f++){
      float4 b4 = bp[f];
      s += b4.x*coef[f*4+0] + b4.y*coef[f*4+1] + b4.z*coef[f*4+2] + b4.w*coef[f*4+3];
    }
    l[i] = s;
  }
  if (proj == 3){
    for (int i=0;i<4;i++){ int v = tid+i*256; Wp[(size_t)v*C_ + c] = l[i]; }
    return;
  }
  // softmax over V (1024 values per column c)
  float mx = fmaxf(fmaxf(l[0],l[1]), fmaxf(l[2],l[3]));
  red[tid] = mx; __syncthreads();
  for (int s=128; s>0; s>>=1){ if (tid<s) red[tid] = fmaxf(red[tid], red[tid+s]); __syncthreads(); }
  mx = red[0]; __syncthreads();
  float sum = 0.f;
  for (int i=0;i<4;i++) sum += expf(l[i]-mx);
  red[tid] = sum; __syncthreads();
  for (int s=128; s>0; s>>=1){ if (tid<s) red[tid] += red[tid+s]; __syncthreads(); }
  float inv = 1.0f/red[0];
  for (int i=0;i<4;i++){ int v = tid+i*256; Wp[(size_t)v*C_ + c] = expf(l[i]-mx)*inv; }
}

// ---------------------------------------------------------------------------
// K1: q/k/v = x @ W  (M=16384, K=1024, N=128), one projection per blockIdx.y
// block computes 64x128 tile; 256 threads, thread tile 8 rows x 4 cols
// ---------------------------------------------------------------------------
__global__ __launch_bounds__(256) void proj_kernel(
    const float* __restrict__ x, const float* __restrict__ W,
    float* __restrict__ out)
{
  const int M = B_*T_;
  int proj = blockIdx.y;
  const float* Wp = W + (size_t)proj*V_*C_;
  float* op = out + (size_t)proj*M*C_;
  int m0 = blockIdx.x * 64;

  __shared__ float xs[64][32];
  __shared__ float ws[32][128];
  int tid = threadIdx.x;
  int tx = tid & 31, ty = tid >> 5;
  float acc[8][4] = {};

  for (int kt = 0; kt < V_/32; kt++){
    #pragma unroll
    for (int i=0;i<2;i++){
      int idx = tid + i*256;            // f4 idx over 64x8
      int row = idx >> 3, c4 = idx & 7;
      *(float4*)&xs[row][c4*4] = *(const float4*)(x + (size_t)(m0+row)*V_ + kt*32 + c4*4);
    }
    #pragma unroll
    for (int i=0;i<4;i++){
      int idx = tid + i*256;            // f4 idx over 32x32
      int kk = idx >> 5, c4 = idx & 31;
      *(float4*)&ws[kk][c4*4] = *(const float4*)(Wp + (size_t)(kt*32+kk)*C_ + c4*4);
    }
    __syncthreads();
    #pragma unroll
    for (int k4 = 0; k4 < 8; k4++){
      float4 wv[4];
      #pragma unroll
      for (int i=0;i<4;i++) wv[i] = *(float4*)&ws[k4*4+i][tx*4];
      #pragma unroll
      for (int r=0;r<8;r++){
        float4 xv = *(float4*)&xs[ty*8+r][k4*4];
        acc[r][0] += xv.x*wv[0].x + xv.y*wv[1].x + xv.z*wv[2].x + xv.w*wv[3].x;
        acc[r][1] += xv.x*wv[0].y + xv.y*wv[1].y + xv.z*wv[2].y + xv.w*wv[3].y;
        acc[r][2] += xv.x*wv[0].z + xv.y*wv[1].z + xv.z*wv[2].z + xv.w*wv[3].z;
        acc[r][3] += xv.x*wv[0].w + xv.y*wv[1].w + xv.z*wv[2].w + xv.w*wv[3].w;
      }
    }
    __syncthreads();
  }
  for (int r=0;r<8;r++){
    *(float4*)(op + (size_t)(m0+ty*8+r)*C_ + tx*4) =
        make_float4(acc[r][0],acc[r][1],acc[r][2],acc[r][3]);
  }
}

// ---------------------------------------------------------------------------
// K2: per-chunk KV summary: kv[b][ci][c][dd] = sum_j d^{L-1-j} k_j[c] v_j[dd]
// grid (NC_, B_), 256 threads (16x16), thread tile 8x8
// ---------------------------------------------------------------------------
__global__ __launch_bounds__(256) void kvsum_kernel(
    const float* __restrict__ k, const float* __restrict__ v,
    const float* __restrict__ dptr, float* __restrict__ kv)
{
  int ci = blockIdx.x, b = blockIdx.y;
  float d = sigmoidf_(dptr[0]);
  __shared__ float ks[L_][132];
  __shared__ float vs[L_][132];
  int tid = threadIdx.x;
  const float* kp = k + ((size_t)b*T_ + ci*L_)*C_;
  const float* vp = v + ((size_t)b*T_ + ci*L_)*C_;
  #pragma unroll
  for (int i=0;i<4;i++){
    int idx = tid + i*256;              // f4 idx over 32x32
    int j = idx >> 5, c4 = idx & 31;
    float w = powf(d, (float)(L_-1-j));
    float4 k4 = *(const float4*)(kp + (size_t)j*C_ + c4*4);
    k4.x*=w; k4.y*=w; k4.z*=w; k4.w*=w;
    *(float4*)&ks[j][c4*4] = k4;
    *(float4*)&vs[j][c4*4] = *(const float4*)(vp + (size_t)j*C_ + c4*4);
  }
  __syncthreads();
  int tc = tid >> 4, td = tid & 15;
  float acc[8][8] = {};
  for (int j=0;j<L_;j++){
    float kr[8], vr[8];
    *(float4*)&kr[0] = *(float4*)&ks[j][tc*8];
    *(float4*)&kr[4] = *(float4*)&ks[j][tc*8+4];
    *(float4*)&vr[0] = *(float4*)&vs[j][td*8];
    *(float4*)&vr[4] = *(float4*)&vs[j][td*8+4];
    #pragma unroll
    for (int a=0;a<8;a++)
      #pragma unroll
      for (int bb=0;bb<8;bb++) acc[a][bb] += kr[a]*vr[bb];
  }
  float* op = kv + ((size_t)b*NC_ + ci)*C_*C_;
  for (int a=0;a<8;a++)
    for (int b4=0;b4<2;b4++)
      *(float4*)(op + (size_t)(tc*8+a)*C_ + td*8 + b4*4) =
        make_float4(acc[a][b4*4],acc[a][b4*4+1],acc[a][b4*4+2],acc[a][b4*4+3]);
}

// ---------------------------------------------------------------------------
// K3: in-place exclusive scan over chunks: kv[i] <- Minit_i,
//     Minit_{i+1} = d^L * Minit_i + KVsum_i
// ---------------------------------------------------------------------------
__global__ __launch_bounds__(256) void scan_kernel(
    float* __restrict__ kv, const float* __restrict__ dptr)
{
  int idx = blockIdx.x*256 + threadIdx.x;   // 0..8*16384-1
  int b = idx >> 14, e = idx & 16383;
  float d  = sigmoidf_(dptr[0]);
  float dL = powf(d, (float)L_);
  float* p = kv + (size_t)b*NC_*C_*C_ + e;
  float m = 0.f;
  for (int i=0;i<NC_;i++){
    float s = p[(size_t)i*C_*C_];
    p[(size_t)i*C_*C_] = m;
    m = dL*m + s;
  }
}

// ---------------------------------------------------------------------------
// K4: per-chunk retrieved:
//   ret_r = d^r * q_r @ Minit + sum_{j<r} d^{r-1-j} (q_r . k_j) v_j
// grid (NC_, B_), 256 threads
// ---------------------------------------------------------------------------
__global__ __launch_bounds__(256) void intra_kernel(
    const float* __restrict__ q, const float* __restrict__ k,
    const float* __restrict__ v, const float* __restrict__ Minit,
    const float* __restrict__ dptr, float* __restrict__ ret)
{
  int ci = blockIdx.x, b = blockIdx.y;
  int tid = threadIdx.x;
  float d = sigmoidf_(dptr[0]);
  __shared__ float qs[L_][132];
  __shared__ float kvs[L_][132];     // holds K in phase A, V in phase B
  __shared__ float ps[L_][33];
  __shared__ float dpow[L_+1];
  if (tid <= L_) dpow[tid] = powf(d, (float)tid);

  const float* qp = q + ((size_t)b*T_ + ci*L_)*C_;
  const float* kp = k + ((size_t)b*T_ + ci*L_)*C_;
  const float* vp = v + ((size_t)b*T_ + ci*L_)*C_;
  #pragma unroll
  for (int i=0;i<4;i++){
    int idx = tid + i*256;
    int j = idx >> 5, c4 = idx & 31;
    *(float4*)&qs[j][c4*4]  = *(const float4*)(qp + (size_t)j*C_ + c4*4);
    *(float4*)&kvs[j][c4*4] = *(const float4*)(kp + (size_t)j*C_ + c4*4);
  }
  __syncthreads();

  // Phase A: S = Q K^T (L x L), masked+decayed into ps
  {
    int tr = tid >> 4, tj = tid & 15;  // 2x2 thread tile
    float s[2][2] = {};
    for (int c4=0;c4<32;c4++){
      float4 q4[2], k4[2];
      #pragma unroll
      for (int i=0;i<2;i++) q4[i] = *(float4*)&qs[tr*2+i][c4*4];
      #pragma unroll
      for (int i=0;i<2;i++) k4[i] = *(float4*)&kvs[tj*2+i][c4*4];
      #pragma unroll
      for (int a=0;a<2;a++)
        #pragma unroll
        for (int bb=0;bb<2;bb++)
          s[a][bb] += q4[a].x*k4[bb].x + q4[a].y*k4[bb].y + q4[a].z*k4[bb].z + q4[a].w*k4[bb].w;
    }
    #pragma unroll
    for (int a=0;a<2;a++)
      #pragma unroll
      for (int bb=0;bb<2;bb++){
        int r = tr*2+a, j = tj*2+bb;
        ps[r][j] = (j < r) ? s[a][bb]*dpow[r-1-j] : 0.f;
      }
  }
  __syncthreads();
  // reload kvs with V
  #pragma unroll
  for (int i=0;i<4;i++){
    int idx = tid + i*256;
    int j = idx >> 5, c4 = idx & 31;
    *(float4*)&kvs[j][c4*4] = *(const float4*)(vp + (size_t)j*C_ + c4*4);
  }
  __syncthreads();

  // Phase B: out(32x128) = diag(d^r) Q@Minit + P@V ; thread tile 4x4
  int tx = tid & 31, ty = tid >> 5;
  float acc[4][4] = {};
  const float* Mp = Minit + ((size_t)b*NC_ + ci)*C_*C_;
  for (int c=0;c<C_;c++){
    float4 m4 = *(const float4*)(Mp + (size_t)c*C_ + tx*4);
    #pragma unroll
    for (int r=0;r<4;r++){
      float qv = qs[ty*4+r][c];
      acc[r][0] += qv*m4.x; acc[r][1] += qv*m4.y; acc[r][2] += qv*m4.z; acc[r][3] += qv*m4.w;
    }
  }
  #pragma unroll
  for (int r=0;r<4;r++){
    float sc = dpow[ty*4+r];
    #pragma unroll
    for (int j=0;j<4;j++) acc[r][j] *= sc;
  }
  for (int j=0;j<L_;j++){
    float4 v4 = *(float4*)&kvs[j][tx*4];
    #pragma unroll
    for (int r=0;r<4;r++){
      float p = ps[ty*4+r][j];
      acc[r][0] += p*v4.x; acc[r][1] += p*v4.y; acc[r][2] += p*v4.z; acc[r][3] += p*v4.w;
    }
  }
  float* rp = ret + ((size_t)b*T_ + ci*L_)*C_;
  for (int r=0;r<4;r++)
    *(float4*)(rp + (size_t)(ty*4+r)*C_ + tx*4) =
      make_float4(acc[r][0],acc[r][1],acc[r][2],acc[r][3]);
}

// ---------------------------------------------------------------------------
// K5: out = (retrieved @ Wo^T) * out_scale  (M=16384, K=128, N=1024)
// block 64x128 tile; Wo is (V,C) row-major, transposed on LDS load
// ---------------------------------------------------------------------------
__global__ __launch_bounds__(256) void out_kernel(
    const float* __restrict__ ret, const float* __restrict__ Wo,
    const float* __restrict__ scl, float* __restrict__ out)
{
  int m0 = blockIdx.x * 64;
  int n0 = blockIdx.y * 128;
  float osc = scl[0];
  __shared__ float as[64][32];
  __shared__ float bs[32][132];
  int tid = threadIdx.x;
  int tx = tid & 31, ty = tid >> 5;
  float acc[8][4] = {};

  for (int kt=0; kt<4; kt++){
    #pragma unroll
    for (int i=0;i<2;i++){
      int idx = tid + i*256;
      int row = idx >> 3, c4 = idx & 7;
      *(float4*)&as[row][c4*4] = *(const float4*)(ret + (size_t)(m0+row)*C_ + kt*32 + c4*4);
    }
    #pragma unroll
    for (int i=0;i<4;i++){
      int idx = tid + i*256;            // 128 rows x 8 f4
      int nl = idx >> 3, c4 = idx & 7;
      float4 w4 = *(const float4*)(Wo + (size_t)(n0+nl)*C_ + kt*32 + c4*4);
      bs[c4*4+0][nl] = w4.x;
      bs[c4*4+1][nl] = w4.y;
      bs[c4*4+2][nl] = w4.z;
      bs[c4*4+3][nl] = w4.w;
    }
    __syncthreads();
    #pragma unroll
    for (int k4=0;k4<8;k4++){
      float4 wv[4];
      #pragma unroll
      for (int i=0;i<4;i++) wv[i] = *(float4*)&bs[k4*4+i][tx*4];
      #pragma unroll
      for (int r=0;r<8;r++){
        float4 av = *(float4*)&as[ty*8+r][k4*4];
        acc[r][0] += av.x*wv[0].x + av.y*wv[1].x + av.z*wv[2].x + av.w*wv[3].x;
        acc[r][1] += av.x*wv[0].y + av.y*wv[1].y + av.z*wv[2].y + av.w*wv[3].y;
        acc[r][2] += av.x*wv[0].z + av.y*wv[1].z + av.z*wv[2].z + av.w*wv[3].z;
        acc[r][3] += av.x*wv[0].w + av.y*wv[1].w + av.z*wv[2].w + av.w*wv[3].w;
      }
    }
    __syncthreads();
  }
  for (int r=0;r<8;r++)
    *(float4*)(out + (size_t)(m0+ty*8+r)*V_ + n0 + tx*4) =
      make_float4(acc[r][0]*osc, acc[r][1]*osc, acc[r][2]*osc, acc[r][3]*osc);
}

// ---------------------------------------------------------------------------
extern "C" void kernel_launch(void* const* d_in, const int* in_sizes, int n_in,
                              void* d_out, int out_size, void* d_ws, size_t ws_size,
                              hipStream_t stream)
{
  const float* x     = (const float*)d_in[0];
  const float* basis = (const float*)d_in[1];
  const float* qc    = (const float*)d_in[2];
  const float* kc    = (const float*)d_in[3];
  const float* vc    = (const float*)d_in[4];
  const float* oc    = (const float*)d_in[5];
  const float* dptr  = (const float*)d_in[6];
  const float* sptr  = (const float*)d_in[7];
  float* out = (float*)d_out;
  float* ws  = (float*)d_ws;

  const size_t M = (size_t)B_*T_;
  float* W   = ws;                         // 4*V*C        = 524288 floats
  float* qkv = W + 4*(size_t)V_*C_;        // 3*M*C        = 6291456
  float* ret = qkv + 3*M*C_;               // M*C          = 2097152
  float* kv  = ret + M*C_;                 // B*NC*C*C     = 8388608
                                           // total ~69 MB fp32

  float* q = qkv;
  float* k = qkv + M*C_;
  float* v = qkv + 2*M*C_;

  hipLaunchKernelGGL(weights_kernel, dim3(512), dim3(256), 0, stream,
                     basis, qc, kc, vc, oc, W);
  hipLaunchKernelGGL(proj_kernel, dim3(256,3), dim3(256), 0, stream, x, W, qkv);
  hipLaunchKernelGGL(kvsum_kernel, dim3(NC_, B_), dim3(256), 0, stream, k, v, dptr, kv);
  hipLaunchKernelGGL(scan_kernel, dim3(512), dim3(256), 0, stream, kv, dptr);
  hipLaunchKernelGGL(intra_kernel, dim3(NC_, B_), dim3(256), 0, stream,
                     q, k, v, kv, dptr, ret);
  hipLaunchKernelGGL(out_kernel, dim3(256, 8), dim3(256), 0, stream,
                     ret, W + 3*(size_t)V_*C_, sptr, out);
}

// Round 3
// 374.181 us; speedup vs baseline: 1.6252x; 1.6252x over previous
//
#include <hip/hip_runtime.h>
#include <math.h>

// Problem constants
#define B_   8
#define T_   2048
#define V_   1024
#define C_   128
#define NB2  64     // 2*NB
#define L_   32     // chunk length for the linearized recurrence
#define NC_  64     // T_/L_

typedef __bf16 bf16_t;
typedef bf16_t bf16x8 __attribute__((ext_vector_type(8)));
typedef float  f32x4  __attribute__((ext_vector_type(4)));

__device__ __forceinline__ float sigmoidf_(float x){ return 1.0f/(1.0f+expf(-x)); }

// ---------------------------------------------------------------------------
// K0: weights. proj 0..2: softmax(basis@coeffs^T, axis=V) -> bf16 split,
//     TRANSPOSED (Wt[c][v]) for MFMA B-fragment reads. proj 3: fp32 Wo (V,C).
// grid: 4*128 blocks (proj,c), 256 threads
// ---------------------------------------------------------------------------
__global__ __launch_bounds__(256) void weights_kernel(
    const float* __restrict__ basis,
    const float* __restrict__ qc, const float* __restrict__ kc,
    const float* __restrict__ vc, const float* __restrict__ oc,
    float* __restrict__ Wo, bf16_t* __restrict__ Wth, bf16_t* __restrict__ Wtl)
{
  int blk  = blockIdx.x;
  int proj = blk >> 7;
  int c    = blk & 127;
  const float* coeffs = (proj==0)?qc : (proj==1)?kc : (proj==2)?vc : oc;

  __shared__ float coef[NB2];
  __shared__ float red[256];
  int tid = threadIdx.x;
  if (tid < NB2) coef[tid] = coeffs[c*NB2 + tid];
  __syncthreads();

  float l[4];
  for (int i=0;i<4;i++){
    int v = tid + i*256;
    const float4* bp = (const float4*)(basis + (size_t)v*NB2);
    float s = 0.f;
    #pragma unroll
    for (int f=0; f<NB2/4; f++){
      float4 b4 = bp[f];
      s += b4.x*coef[f*4+0] + b4.y*coef[f*4+1] + b4.z*coef[f*4+2] + b4.w*coef[f*4+3];
    }
    l[i] = s;
  }
  if (proj == 3){
    for (int i=0;i<4;i++){ int v = tid+i*256; Wo[(size_t)v*C_ + c] = l[i]; }
    return;
  }
  // softmax over V (1024 values per column c)
  float mx = fmaxf(fmaxf(l[0],l[1]), fmaxf(l[2],l[3]));
  red[tid] = mx; __syncthreads();
  for (int s=128; s>0; s>>=1){ if (tid<s) red[tid] = fmaxf(red[tid], red[tid+s]); __syncthreads(); }
  mx = red[0]; __syncthreads();
  float sum = 0.f;
  for (int i=0;i<4;i++) sum += expf(l[i]-mx);
  red[tid] = sum; __syncthreads();
  for (int s=128; s>0; s>>=1){ if (tid<s) red[tid] += red[tid+s]; __syncthreads(); }
  float inv = 1.0f/red[0];
  bf16_t* th = Wth + ((size_t)proj*C_ + c)*V_;
  bf16_t* tl = Wtl + ((size_t)proj*C_ + c)*V_;
  for (int i=0;i<4;i++){
    int v = tid+i*256;
    float wv = expf(l[i]-mx)*inv;
    bf16_t h = (bf16_t)wv;
    bf16_t lo = (bf16_t)(wv - (float)h);
    th[v] = h; tl[v] = lo;
  }
}

// ---------------------------------------------------------------------------
// K1: q/k/v = x @ W via split-bf16 MFMA:  x=(xh+xl), W=(Wh+Wl);
//     acc += xh*Wh + xl*Wh + xh*Wl   (xl*Wl term ~2^-16 rel, dropped)
// 64x128 block tile, BK=64, 256 threads = 4 waves (2x2), 16x16x32 bf16 MFMA.
// Wave tile 32x64: mt in {0,1}, nt in {0..3}.
// ---------------------------------------------------------------------------
#define BM 64
#define BN 128
#define BK 64
#define PADK 72   // LDS row stride in bf16 (144 B, 16B-aligned, breaks pow2 banks)

__global__ __launch_bounds__(256, 2) void proj_mfma_kernel(
    const float* __restrict__ x,
    const bf16_t* __restrict__ Wth, const bf16_t* __restrict__ Wtl,
    float* __restrict__ out)
{
  const int M = B_*T_;
  int proj = blockIdx.y;
  int m0   = blockIdx.x * BM;
  float* op = out + (size_t)proj*M*C_;
  const bf16_t* bhp = Wth + (size_t)proj*C_*V_;
  const bf16_t* blp = Wtl + (size_t)proj*C_*V_;

  __shared__ bf16_t Ah[BM][PADK];
  __shared__ bf16_t Al[BM][PADK];
  __shared__ bf16_t Bh[BN][PADK];
  __shared__ bf16_t Bl[BN][PADK];

  int tid  = threadIdx.x;
  int lane = tid & 63;
  int w    = tid >> 6;
  int wm   = (w >> 1) * 32;   // wave row base
  int wn   = (w & 1) * 64;    // wave col base
  int lr   = lane & 15;
  int lg   = lane >> 4;

  f32x4 acc[2][4] = {};

  for (int kt = 0; kt < V_/BK; kt++){
    // ---- stage A: read fp32 x, split to (h,l) bf16 ----
    #pragma unroll
    for (int i=0;i<4;i++){
      int f4  = tid + i*256;          // 1024 float4 chunks = 64 rows x 16
      int row = f4 >> 4, q = f4 & 15;
      float4 xv = *(const float4*)(x + (size_t)(m0+row)*V_ + kt*BK + q*4);
      float f[4] = {xv.x, xv.y, xv.z, xv.w};
      union { bf16_t b[4]; ushort4 u; } hh, ll;
      #pragma unroll
      for (int j=0;j<4;j++){
        bf16_t h = (bf16_t)f[j];
        hh.b[j] = h;
        ll.b[j] = (bf16_t)(f[j] - (float)h);
      }
      *(ushort4*)&Ah[row][q*4] = hh.u;
      *(ushort4*)&Al[row][q*4] = ll.u;
    }
    // ---- stage B: copy precomputed transposed bf16 W tiles ----
    #pragma unroll
    for (int i=0;i<4;i++){
      int ci = tid + i*256;           // 1024 16B chunks = 128 rows x 8
      int n = ci >> 3, ch = ci & 7;
      *(uint4*)&Bh[n][ch*8] = *(const uint4*)(bhp + (size_t)n*V_ + kt*BK + ch*8);
      *(uint4*)&Bl[n][ch*8] = *(const uint4*)(blp + (size_t)n*V_ + kt*BK + ch*8);
    }
    __syncthreads();

    #pragma unroll
    for (int kh=0; kh<2; kh++){
      bf16x8 a_h[2], a_l[2];
      #pragma unroll
      for (int mt=0; mt<2; mt++){
        a_h[mt] = *(bf16x8*)&Ah[wm + mt*16 + lr][kh*32 + lg*8];
        a_l[mt] = *(bf16x8*)&Al[wm + mt*16 + lr][kh*32 + lg*8];
      }
      #pragma unroll
      for (int nt=0; nt<4; nt++){
        bf16x8 b_h = *(bf16x8*)&Bh[wn + nt*16 + lr][kh*32 + lg*8];
        bf16x8 b_l = *(bf16x8*)&Bl[wn + nt*16 + lr][kh*32 + lg*8];
        #pragma unroll
        for (int mt=0; mt<2; mt++){
          acc[mt][nt] = __builtin_amdgcn_mfma_f32_16x16x32_bf16(a_h[mt], b_h, acc[mt][nt], 0,0,0);
          acc[mt][nt] = __builtin_amdgcn_mfma_f32_16x16x32_bf16(a_l[mt], b_h, acc[mt][nt], 0,0,0);
          acc[mt][nt] = __builtin_amdgcn_mfma_f32_16x16x32_bf16(a_h[mt], b_l, acc[mt][nt], 0,0,0);
        }
      }
    }
    __syncthreads();
  }

  // epilogue: C/D layout col=lane&15, row=(lane>>4)*4+reg
  #pragma unroll
  for (int mt=0; mt<2; mt++)
    #pragma unroll
    for (int nt=0; nt<4; nt++)
      #pragma unroll
      for (int r=0; r<4; r++){
        int row = m0 + wm + mt*16 + lg*4 + r;
        int col = wn + nt*16 + lr;
        op[(size_t)row*C_ + col] = acc[mt][nt][r];
      }
}

// ---------------------------------------------------------------------------
// K2: per-chunk KV summary: kv[b][ci][c][dd] = sum_j d^{L-1-j} k_j[c] v_j[dd]
// ---------------------------------------------------------------------------
__global__ __launch_bounds__(256) void kvsum_kernel(
    const float* __restrict__ k, const float* __restrict__ v,
    const float* __restrict__ dptr, float* __restrict__ kv)
{
  int ci = blockIdx.x, b = blockIdx.y;
  float d = sigmoidf_(dptr[0]);
  __shared__ float ks[L_][132];
  __shared__ float vs[L_][132];
  int tid = threadIdx.x;
  const float* kp = k + ((size_t)b*T_ + ci*L_)*C_;
  const float* vp = v + ((size_t)b*T_ + ci*L_)*C_;
  #pragma unroll
  for (int i=0;i<4;i++){
    int idx = tid + i*256;
    int j = idx >> 5, c4 = idx & 31;
    float w = powf(d, (float)(L_-1-j));
    float4 k4 = *(const float4*)(kp + (size_t)j*C_ + c4*4);
    k4.x*=w; k4.y*=w; k4.z*=w; k4.w*=w;
    *(float4*)&ks[j][c4*4] = k4;
    *(float4*)&vs[j][c4*4] = *(const float4*)(vp + (size_t)j*C_ + c4*4);
  }
  __syncthreads();
  int tc = tid >> 4, td = tid & 15;
  float acc[8][8] = {};
  for (int j=0;j<L_;j++){
    float kr[8], vr[8];
    *(float4*)&kr[0] = *(float4*)&ks[j][tc*8];
    *(float4*)&kr[4] = *(float4*)&ks[j][tc*8+4];
    *(float4*)&vr[0] = *(float4*)&vs[j][td*8];
    *(float4*)&vr[4] = *(float4*)&vs[j][td*8+4];
    #pragma unroll
    for (int a=0;a<8;a++)
      #pragma unroll
      for (int bb=0;bb<8;bb++) acc[a][bb] += kr[a]*vr[bb];
  }
  float* op = kv + ((size_t)b*NC_ + ci)*C_*C_;
  for (int a=0;a<8;a++)
    for (int b4=0;b4<2;b4++)
      *(float4*)(op + (size_t)(tc*8+a)*C_ + td*8 + b4*4) =
        make_float4(acc[a][b4*4],acc[a][b4*4+1],acc[a][b4*4+2],acc[a][b4*4+3]);
}

// ---------------------------------------------------------------------------
// K3: in-place exclusive scan over chunks
// ---------------------------------------------------------------------------
__global__ __launch_bounds__(256) void scan_kernel(
    float* __restrict__ kv, const float* __restrict__ dptr)
{
  int idx = blockIdx.x*256 + threadIdx.x;
  int b = idx >> 14, e = idx & 16383;
  float d  = sigmoidf_(dptr[0]);
  float dL = powf(d, (float)L_);
  float* p = kv + (size_t)b*NC_*C_*C_ + e;
  float m = 0.f;
  for (int i=0;i<NC_;i++){
    float s = p[(size_t)i*C_*C_];
    p[(size_t)i*C_*C_] = m;
    m = dL*m + s;
  }
}

// ---------------------------------------------------------------------------
// K4: per-chunk retrieved
// ---------------------------------------------------------------------------
__global__ __launch_bounds__(256) void intra_kernel(
    const float* __restrict__ q, const float* __restrict__ k,
    const float* __restrict__ v, const float* __restrict__ Minit,
    const float* __restrict__ dptr, float* __restrict__ ret)
{
  int ci = blockIdx.x, b = blockIdx.y;
  int tid = threadIdx.x;
  float d = sigmoidf_(dptr[0]);
  __shared__ float qs[L_][132];
  __shared__ float kvs[L_][132];
  __shared__ float ps[L_][33];
  __shared__ float dpow[L_+1];
  if (tid <= L_) dpow[tid] = powf(d, (float)tid);

  const float* qp = q + ((size_t)b*T_ + ci*L_)*C_;
  const float* kp = k + ((size_t)b*T_ + ci*L_)*C_;
  const float* vp = v + ((size_t)b*T_ + ci*L_)*C_;
  #pragma unroll
  for (int i=0;i<4;i++){
    int idx = tid + i*256;
    int j = idx >> 5, c4 = idx & 31;
    *(float4*)&qs[j][c4*4]  = *(const float4*)(qp + (size_t)j*C_ + c4*4);
    *(float4*)&kvs[j][c4*4] = *(const float4*)(kp + (size_t)j*C_ + c4*4);
  }
  __syncthreads();

  {
    int tr = tid >> 4, tj = tid & 15;
    float s[2][2] = {};
    for (int c4=0;c4<32;c4++){
      float4 q4[2], k4[2];
      #pragma unroll
      for (int i=0;i<2;i++) q4[i] = *(float4*)&qs[tr*2+i][c4*4];
      #pragma unroll
      for (int i=0;i<2;i++) k4[i] = *(float4*)&kvs[tj*2+i][c4*4];
      #pragma unroll
      for (int a=0;a<2;a++)
        #pragma unroll
        for (int bb=0;bb<2;bb++)
          s[a][bb] += q4[a].x*k4[bb].x + q4[a].y*k4[bb].y + q4[a].z*k4[bb].z + q4[a].w*k4[bb].w;
    }
    #pragma unroll
    for (int a=0;a<2;a++)
      #pragma unroll
      for (int bb=0;bb<2;bb++){
        int r = tr*2+a, j = tj*2+bb;
        ps[r][j] = (j < r) ? s[a][bb]*dpow[r-1-j] : 0.f;
      }
  }
  __syncthreads();
  #pragma unroll
  for (int i=0;i<4;i++){
    int idx = tid + i*256;
    int j = idx >> 5, c4 = idx & 31;
    *(float4*)&kvs[j][c4*4] = *(const float4*)(vp + (size_t)j*C_ + c4*4);
  }
  __syncthreads();

  int tx = tid & 31, ty = tid >> 5;
  float acc[4][4] = {};
  const float* Mp = Minit + ((size_t)b*NC_ + ci)*C_*C_;
  for (int c=0;c<C_;c++){
    float4 m4 = *(const float4*)(Mp + (size_t)c*C_ + tx*4);
    #pragma unroll
    for (int r=0;r<4;r++){
      float qv = qs[ty*4+r][c];
      acc[r][0] += qv*m4.x; acc[r][1] += qv*m4.y; acc[r][2] += qv*m4.z; acc[r][3] += qv*m4.w;
    }
  }
  #pragma unroll
  for (int r=0;r<4;r++){
    float sc = dpow[ty*4+r];
    #pragma unroll
    for (int j=0;j<4;j++) acc[r][j] *= sc;
  }
  for (int j=0;j<L_;j++){
    float4 v4 = *(float4*)&kvs[j][tx*4];
    #pragma unroll
    for (int r=0;r<4;r++){
      float p = ps[ty*4+r][j];
      acc[r][0] += p*v4.x; acc[r][1] += p*v4.y; acc[r][2] += p*v4.z; acc[r][3] += p*v4.w;
    }
  }
  float* rp = ret + ((size_t)b*T_ + ci*L_)*C_;
  for (int r=0;r<4;r++)
    *(float4*)(rp + (size_t)(ty*4+r)*C_ + tx*4) =
      make_float4(acc[r][0],acc[r][1],acc[r][2],acc[r][3]);
}

// ---------------------------------------------------------------------------
// K5: out = (retrieved @ Wo^T) * out_scale  (fp32)
// ---------------------------------------------------------------------------
__global__ __launch_bounds__(256) void out_kernel(
    const float* __restrict__ ret, const float* __restrict__ Wo,
    const float* __restrict__ scl, float* __restrict__ out)
{
  int m0 = blockIdx.x * 64;
  int n0 = blockIdx.y * 128;
  float osc = scl[0];
  __shared__ float as[64][32];
  __shared__ float bs[32][132];
  int tid = threadIdx.x;
  int tx = tid & 31, ty = tid >> 5;
  float acc[8][4] = {};

  for (int kt=0; kt<4; kt++){
    #pragma unroll
    for (int i=0;i<2;i++){
      int idx = tid + i*256;
      int row = idx >> 3, c4 = idx & 7;
      *(float4*)&as[row][c4*4] = *(const float4*)(ret + (size_t)(m0+row)*C_ + kt*32 + c4*4);
    }
    #pragma unroll
    for (int i=0;i<4;i++){
      int idx = tid + i*256;
      int nl = idx >> 3, c4 = idx & 7;
      float4 w4 = *(const float4*)(Wo + (size_t)(n0+nl)*C_ + kt*32 + c4*4);
      bs[c4*4+0][nl] = w4.x;
      bs[c4*4+1][nl] = w4.y;
      bs[c4*4+2][nl] = w4.z;
      bs[c4*4+3][nl] = w4.w;
    }
    __syncthreads();
    #pragma unroll
    for (int k4=0;k4<8;k4++){
      float4 wv[4];
      #pragma unroll
      for (int i=0;i<4;i++) wv[i] = *(float4*)&bs[k4*4+i][tx*4];
      #pragma unroll
      for (int r=0;r<8;r++){
        float4 av = *(float4*)&as[ty*8+r][k4*4];
        acc[r][0] += av.x*wv[0].x + av.y*wv[1].x + av.z*wv[2].x + av.w*wv[3].x;
        acc[r][1] += av.x*wv[0].y + av.y*wv[1].y + av.z*wv[2].y + av.w*wv[3].y;
        acc[r][2] += av.x*wv[0].z + av.y*wv[1].z + av.z*wv[2].z + av.w*wv[3].z;
        acc[r][3] += av.x*wv[0].w + av.y*wv[1].w + av.z*wv[2].w + av.w*wv[3].w;
      }
    }
    __syncthreads();
  }
  for (int r=0;r<8;r++)
    *(float4*)(out + (size_t)(m0+ty*8+r)*V_ + n0 + tx*4) =
      make_float4(acc[r][0]*osc, acc[r][1]*osc, acc[r][2]*osc, acc[r][3]*osc);
}

// ---------------------------------------------------------------------------
extern "C" void kernel_launch(void* const* d_in, const int* in_sizes, int n_in,
                              void* d_out, int out_size, void* d_ws, size_t ws_size,
                              hipStream_t stream)
{
  const float* x     = (const float*)d_in[0];
  const float* basis = (const float*)d_in[1];
  const float* qc    = (const float*)d_in[2];
  const float* kc    = (const float*)d_in[3];
  const float* vc    = (const float*)d_in[4];
  const float* oc    = (const float*)d_in[5];
  const float* dptr  = (const float*)d_in[6];
  const float* sptr  = (const float*)d_in[7];
  float* out = (float*)d_out;
  float* ws  = (float*)d_ws;

  const size_t M = (size_t)B_*T_;
  // Workspace layout (float units). NOTE: Wth and Wtl are bf16 — each
  // occupies 3*C*V/2 = 196608 float-equivalents. R2 bug: qkv offset only
  // skipped ONE of the two bf16 arrays, aliasing q onto Wtl -> NaN.
  float*  Wo  = ws;                               // V*C fp32        = 131072 f
  bf16_t* Wth = (bf16_t*)(ws + 131072);           // 3*C*V bf16      = 196608 f-equiv
  bf16_t* Wtl = Wth + 3*(size_t)C_*V_;            // 3*C*V bf16      = 196608 f-equiv
  float*  qkv = ws + 131072 + 196608 + 196608;    // 3*M*C           = 6291456 f
  float*  ret = qkv + 3*M*C_;                     // M*C             = 2097152 f
  float*  kv  = ret + M*C_;                       // B*NC*C*C        = 8388608 f
                                                  // total = 17301504 f = 69.2 MB

  float* q = qkv;
  float* k = qkv + M*C_;
  float* v = qkv + 2*M*C_;

  hipLaunchKernelGGL(weights_kernel, dim3(512), dim3(256), 0, stream,
                     basis, qc, kc, vc, oc, Wo, Wth, Wtl);
  hipLaunchKernelGGL(proj_mfma_kernel, dim3(256,3), dim3(256), 0, stream,
                     x, Wth, Wtl, qkv);
  hipLaunchKernelGGL(kvsum_kernel, dim3(NC_, B_), dim3(256), 0, stream, k, v, dptr, kv);
  hipLaunchKernelGGL(scan_kernel, dim3(512), dim3(256), 0, stream, kv, dptr);
  hipLaunchKernelGGL(intra_kernel, dim3(NC_, B_), dim3(256), 0, stream,
                     q, k, v, kv, dptr, ret);
  hipLaunchKernelGGL(out_kernel, dim3(256, 8), dim3(256), 0, stream,
                     ret, Wo, sptr, out);
}

// Round 4
// 291.293 us; speedup vs baseline: 2.0876x; 1.2846x over previous
//
#include <hip/hip_runtime.h>
#include <math.h>

// Problem constants
#define B_   8
#define T_   2048
#define V_   1024
#define C_   128
#define NB2  64     // 2*NB
#define L_   32     // chunk length for the linearized recurrence
#define NC_  64     // T_/L_

typedef __bf16 bf16_t;
typedef bf16_t bf16x8 __attribute__((ext_vector_type(8)));
typedef float  f32x4  __attribute__((ext_vector_type(4)));

__device__ __forceinline__ float sigmoidf_(float x){ return 1.0f/(1.0f+expf(-x)); }

// ---------------------------------------------------------------------------
// K0: weights. proj 0..2: softmax(basis@coeffs^T, axis=V) -> bf16 split,
//     TRANSPOSED (Wt[c][v]) for MFMA B-fragment reads.
//     proj 3: Wo (V,C) row-major -> bf16 split (rows are B-fragments for out).
// grid: 4*128 blocks (proj,c), 256 threads
// ---------------------------------------------------------------------------
__global__ __launch_bounds__(256) void weights_kernel(
    const float* __restrict__ basis,
    const float* __restrict__ qc, const float* __restrict__ kc,
    const float* __restrict__ vc, const float* __restrict__ oc,
    bf16_t* __restrict__ Woh, bf16_t* __restrict__ Wol,
    bf16_t* __restrict__ Wth, bf16_t* __restrict__ Wtl)
{
  int blk  = blockIdx.x;
  int proj = blk >> 7;
  int c    = blk & 127;
  const float* coeffs = (proj==0)?qc : (proj==1)?kc : (proj==2)?vc : oc;

  __shared__ float coef[NB2];
  __shared__ float red[256];
  int tid = threadIdx.x;
  if (tid < NB2) coef[tid] = coeffs[c*NB2 + tid];
  __syncthreads();

  float l[4];
  for (int i=0;i<4;i++){
    int v = tid + i*256;
    const float4* bp = (const float4*)(basis + (size_t)v*NB2);
    float s = 0.f;
    #pragma unroll
    for (int f=0; f<NB2/4; f++){
      float4 b4 = bp[f];
      s += b4.x*coef[f*4+0] + b4.y*coef[f*4+1] + b4.z*coef[f*4+2] + b4.w*coef[f*4+3];
    }
    l[i] = s;
  }
  if (proj == 3){
    for (int i=0;i<4;i++){
      int v = tid+i*256;
      bf16_t h = (bf16_t)l[i];
      Woh[(size_t)v*C_ + c] = h;
      Wol[(size_t)v*C_ + c] = (bf16_t)(l[i] - (float)h);
    }
    return;
  }
  // softmax over V (1024 values per column c)
  float mx = fmaxf(fmaxf(l[0],l[1]), fmaxf(l[2],l[3]));
  red[tid] = mx; __syncthreads();
  for (int s=128; s>0; s>>=1){ if (tid<s) red[tid] = fmaxf(red[tid], red[tid+s]); __syncthreads(); }
  mx = red[0]; __syncthreads();
  float sum = 0.f;
  for (int i=0;i<4;i++) sum += expf(l[i]-mx);
  red[tid] = sum; __syncthreads();
  for (int s=128; s>0; s>>=1){ if (tid<s) red[tid] += red[tid+s]; __syncthreads(); }
  float inv = 1.0f/red[0];
  bf16_t* th = Wth + ((size_t)proj*C_ + c)*V_;
  bf16_t* tl = Wtl + ((size_t)proj*C_ + c)*V_;
  for (int i=0;i<4;i++){
    int v = tid+i*256;
    float wv = expf(l[i]-mx)*inv;
    bf16_t h = (bf16_t)wv;
    bf16_t lo = (bf16_t)(wv - (float)h);
    th[v] = h; tl[v] = lo;
  }
}

// ---------------------------------------------------------------------------
// K1: q/k/v = x @ W via split-bf16 MFMA:  x=(xh+xl), W=(Wh+Wl);
//     acc += xh*Wh + xl*Wh + xh*Wl   (xl*Wl term ~2^-16 rel, dropped)
// 64x128 block tile, BK=64, 256 threads = 4 waves (2x2), 16x16x32 bf16 MFMA.
// ---------------------------------------------------------------------------
#define BM 64
#define BN 128
#define BK 64
#define PADK 72   // LDS row stride in bf16 (144 B, 16B-aligned, breaks pow2 banks)

__global__ __launch_bounds__(256, 2) void proj_mfma_kernel(
    const float* __restrict__ x,
    const bf16_t* __restrict__ Wth, const bf16_t* __restrict__ Wtl,
    float* __restrict__ out)
{
  const int M = B_*T_;
  int proj = blockIdx.y;
  int m0   = blockIdx.x * BM;
  float* op = out + (size_t)proj*M*C_;
  const bf16_t* bhp = Wth + (size_t)proj*C_*V_;
  const bf16_t* blp = Wtl + (size_t)proj*C_*V_;

  __shared__ bf16_t Ah[BM][PADK];
  __shared__ bf16_t Al[BM][PADK];
  __shared__ bf16_t Bh[BN][PADK];
  __shared__ bf16_t Bl[BN][PADK];

  int tid  = threadIdx.x;
  int lane = tid & 63;
  int w    = tid >> 6;
  int wm   = (w >> 1) * 32;
  int wn   = (w & 1) * 64;
  int lr   = lane & 15;
  int lg   = lane >> 4;

  f32x4 acc[2][4] = {};

  for (int kt = 0; kt < V_/BK; kt++){
    // ---- stage A: read fp32 x, split to (h,l) bf16 ----
    #pragma unroll
    for (int i=0;i<4;i++){
      int f4  = tid + i*256;          // 1024 float4 chunks = 64 rows x 16
      int row = f4 >> 4, q = f4 & 15;
      float4 xv = *(const float4*)(x + (size_t)(m0+row)*V_ + kt*BK + q*4);
      float f[4] = {xv.x, xv.y, xv.z, xv.w};
      union { bf16_t b[4]; ushort4 u; } hh, ll;
      #pragma unroll
      for (int j=0;j<4;j++){
        bf16_t h = (bf16_t)f[j];
        hh.b[j] = h;
        ll.b[j] = (bf16_t)(f[j] - (float)h);
      }
      *(ushort4*)&Ah[row][q*4] = hh.u;
      *(ushort4*)&Al[row][q*4] = ll.u;
    }
    // ---- stage B: copy precomputed transposed bf16 W tiles ----
    #pragma unroll
    for (int i=0;i<4;i++){
      int ci = tid + i*256;           // 1024 16B chunks = 128 rows x 8
      int n = ci >> 3, ch = ci & 7;
      *(uint4*)&Bh[n][ch*8] = *(const uint4*)(bhp + (size_t)n*V_ + kt*BK + ch*8);
      *(uint4*)&Bl[n][ch*8] = *(const uint4*)(blp + (size_t)n*V_ + kt*BK + ch*8);
    }
    __syncthreads();

    #pragma unroll
    for (int kh=0; kh<2; kh++){
      bf16x8 a_h[2], a_l[2];
      #pragma unroll
      for (int mt=0; mt<2; mt++){
        a_h[mt] = *(bf16x8*)&Ah[wm + mt*16 + lr][kh*32 + lg*8];
        a_l[mt] = *(bf16x8*)&Al[wm + mt*16 + lr][kh*32 + lg*8];
      }
      #pragma unroll
      for (int nt=0; nt<4; nt++){
        bf16x8 b_h = *(bf16x8*)&Bh[wn + nt*16 + lr][kh*32 + lg*8];
        bf16x8 b_l = *(bf16x8*)&Bl[wn + nt*16 + lr][kh*32 + lg*8];
        #pragma unroll
        for (int mt=0; mt<2; mt++){
          acc[mt][nt] = __builtin_amdgcn_mfma_f32_16x16x32_bf16(a_h[mt], b_h, acc[mt][nt], 0,0,0);
          acc[mt][nt] = __builtin_amdgcn_mfma_f32_16x16x32_bf16(a_l[mt], b_h, acc[mt][nt], 0,0,0);
          acc[mt][nt] = __builtin_amdgcn_mfma_f32_16x16x32_bf16(a_h[mt], b_l, acc[mt][nt], 0,0,0);
        }
      }
    }
    __syncthreads();
  }

  // epilogue: C/D layout col=lane&15, row=(lane>>4)*4+reg
  #pragma unroll
  for (int mt=0; mt<2; mt++)
    #pragma unroll
    for (int nt=0; nt<4; nt++)
      #pragma unroll
      for (int r=0; r<4; r++){
        int row = m0 + wm + mt*16 + lg*4 + r;
        int col = wn + nt*16 + lr;
        op[(size_t)row*C_ + col] = acc[mt][nt][r];
      }
}

// ---------------------------------------------------------------------------
// K2: per-chunk KV summary: kv[b][ci][c][dd] = sum_j d^{L-1-j} k_j[c] v_j[dd]
// ---------------------------------------------------------------------------
__global__ __launch_bounds__(256) void kvsum_kernel(
    const float* __restrict__ k, const float* __restrict__ v,
    const float* __restrict__ dptr, float* __restrict__ kv)
{
  int ci = blockIdx.x, b = blockIdx.y;
  float d = sigmoidf_(dptr[0]);
  __shared__ float ks[L_][132];
  __shared__ float vs[L_][132];
  int tid = threadIdx.x;
  const float* kp = k + ((size_t)b*T_ + ci*L_)*C_;
  const float* vp = v + ((size_t)b*T_ + ci*L_)*C_;
  #pragma unroll
  for (int i=0;i<4;i++){
    int idx = tid + i*256;
    int j = idx >> 5, c4 = idx & 31;
    float w = powf(d, (float)(L_-1-j));
    float4 k4 = *(const float4*)(kp + (size_t)j*C_ + c4*4);
    k4.x*=w; k4.y*=w; k4.z*=w; k4.w*=w;
    *(float4*)&ks[j][c4*4] = k4;
    *(float4*)&vs[j][c4*4] = *(const float4*)(vp + (size_t)j*C_ + c4*4);
  }
  __syncthreads();
  int tc = tid >> 4, td = tid & 15;
  float acc[8][8] = {};
  for (int j=0;j<L_;j++){
    float kr[8], vr[8];
    *(float4*)&kr[0] = *(float4*)&ks[j][tc*8];
    *(float4*)&kr[4] = *(float4*)&ks[j][tc*8+4];
    *(float4*)&vr[0] = *(float4*)&vs[j][td*8];
    *(float4*)&vr[4] = *(float4*)&vs[j][td*8+4];
    #pragma unroll
    for (int a=0;a<8;a++)
      #pragma unroll
      for (int bb=0;bb<8;bb++) acc[a][bb] += kr[a]*vr[bb];
  }
  float* op = kv + ((size_t)b*NC_ + ci)*C_*C_;
  for (int a=0;a<8;a++)
    for (int b4=0;b4<2;b4++)
      *(float4*)(op + (size_t)(tc*8+a)*C_ + td*8 + b4*4) =
        make_float4(acc[a][b4*4],acc[a][b4*4+1],acc[a][b4*4+2],acc[a][b4*4+3]);
}

// ---------------------------------------------------------------------------
// K3: in-place exclusive scan over chunks
// ---------------------------------------------------------------------------
__global__ __launch_bounds__(256) void scan_kernel(
    float* __restrict__ kv, const float* __restrict__ dptr)
{
  int idx = blockIdx.x*256 + threadIdx.x;
  int b = idx >> 14, e = idx & 16383;
  float d  = sigmoidf_(dptr[0]);
  float dL = powf(d, (float)L_);
  float* p = kv + (size_t)b*NC_*C_*C_ + e;
  float m = 0.f;
  for (int i=0;i<NC_;i++){
    float s = p[(size_t)i*C_*C_];
    p[(size_t)i*C_*C_] = m;
    m = dL*m + s;
  }
}

// ---------------------------------------------------------------------------
// K4: per-chunk retrieved; epilogue writes ret as bf16 hi/lo (feeds out MFMA)
// ---------------------------------------------------------------------------
__global__ __launch_bounds__(256) void intra_kernel(
    const float* __restrict__ q, const float* __restrict__ k,
    const float* __restrict__ v, const float* __restrict__ Minit,
    const float* __restrict__ dptr,
    bf16_t* __restrict__ reth, bf16_t* __restrict__ retl)
{
  int ci = blockIdx.x, b = blockIdx.y;
  int tid = threadIdx.x;
  float d = sigmoidf_(dptr[0]);
  __shared__ float qs[L_][132];
  __shared__ float kvs[L_][132];
  __shared__ float ps[L_][33];
  __shared__ float dpow[L_+1];
  if (tid <= L_) dpow[tid] = powf(d, (float)tid);

  const float* qp = q + ((size_t)b*T_ + ci*L_)*C_;
  const float* kp = k + ((size_t)b*T_ + ci*L_)*C_;
  const float* vp = v + ((size_t)b*T_ + ci*L_)*C_;
  #pragma unroll
  for (int i=0;i<4;i++){
    int idx = tid + i*256;
    int j = idx >> 5, c4 = idx & 31;
    *(float4*)&qs[j][c4*4]  = *(const float4*)(qp + (size_t)j*C_ + c4*4);
    *(float4*)&kvs[j][c4*4] = *(const float4*)(kp + (size_t)j*C_ + c4*4);
  }
  __syncthreads();

  {
    int tr = tid >> 4, tj = tid & 15;
    float s[2][2] = {};
    for (int c4=0;c4<32;c4++){
      float4 q4[2], k4[2];
      #pragma unroll
      for (int i=0;i<2;i++) q4[i] = *(float4*)&qs[tr*2+i][c4*4];
      #pragma unroll
      for (int i=0;i<2;i++) k4[i] = *(float4*)&kvs[tj*2+i][c4*4];
      #pragma unroll
      for (int a=0;a<2;a++)
        #pragma unroll
        for (int bb=0;bb<2;bb++)
          s[a][bb] += q4[a].x*k4[bb].x + q4[a].y*k4[bb].y + q4[a].z*k4[bb].z + q4[a].w*k4[bb].w;
    }
    #pragma unroll
    for (int a=0;a<2;a++)
      #pragma unroll
      for (int bb=0;bb<2;bb++){
        int r = tr*2+a, j = tj*2+bb;
        ps[r][j] = (j < r) ? s[a][bb]*dpow[r-1-j] : 0.f;
      }
  }
  __syncthreads();
  #pragma unroll
  for (int i=0;i<4;i++){
    int idx = tid + i*256;
    int j = idx >> 5, c4 = idx & 31;
    *(float4*)&kvs[j][c4*4] = *(const float4*)(vp + (size_t)j*C_ + c4*4);
  }
  __syncthreads();

  int tx = tid & 31, ty = tid >> 5;
  float acc[4][4] = {};
  const float* Mp = Minit + ((size_t)b*NC_ + ci)*C_*C_;
  for (int c=0;c<C_;c++){
    float4 m4 = *(const float4*)(Mp + (size_t)c*C_ + tx*4);
    #pragma unroll
    for (int r=0;r<4;r++){
      float qv = qs[ty*4+r][c];
      acc[r][0] += qv*m4.x; acc[r][1] += qv*m4.y; acc[r][2] += qv*m4.z; acc[r][3] += qv*m4.w;
    }
  }
  #pragma unroll
  for (int r=0;r<4;r++){
    float sc = dpow[ty*4+r];
    #pragma unroll
    for (int j=0;j<4;j++) acc[r][j] *= sc;
  }
  for (int j=0;j<L_;j++){
    float4 v4 = *(float4*)&kvs[j][tx*4];
    #pragma unroll
    for (int r=0;r<4;r++){
      float p = ps[ty*4+r][j];
      acc[r][0] += p*v4.x; acc[r][1] += p*v4.y; acc[r][2] += p*v4.z; acc[r][3] += p*v4.w;
    }
  }
  size_t rbase = ((size_t)b*T_ + ci*L_)*C_;
  for (int r=0;r<4;r++){
    union { bf16_t b[4]; ushort4 u; } hh, ll;
    #pragma unroll
    for (int j=0;j<4;j++){
      bf16_t h = (bf16_t)acc[r][j];
      hh.b[j] = h;
      ll.b[j] = (bf16_t)(acc[r][j] - (float)h);
    }
    size_t off = rbase + (size_t)(ty*4+r)*C_ + tx*4;
    *(ushort4*)(reth + off) = hh.u;
    *(ushort4*)(retl + off) = ll.u;
  }
}

// ---------------------------------------------------------------------------
// K5: out = (ret @ Wo^T) * out_scale via split-bf16 MFMA.
// M=16384, N=1024, K=128. BM=64, BN=128, kt loop 2x BK=64.
// A = ret (M,C) bf16 h/l; B = Wo (V,C) bf16 h/l (rows = B-fragments).
// ---------------------------------------------------------------------------
__global__ __launch_bounds__(256, 2) void out_mfma_kernel(
    const bf16_t* __restrict__ Ath, const bf16_t* __restrict__ Atl,
    const bf16_t* __restrict__ Bth, const bf16_t* __restrict__ Btl,
    const float* __restrict__ scl, float* __restrict__ out)
{
  int m0 = blockIdx.x * BM;
  int n0 = blockIdx.y * BN;
  float osc = scl[0];

  __shared__ bf16_t Ah[BM][PADK];
  __shared__ bf16_t Al[BM][PADK];
  __shared__ bf16_t Bh[BN][PADK];
  __shared__ bf16_t Bl[BN][PADK];

  int tid  = threadIdx.x;
  int lane = tid & 63;
  int w    = tid >> 6;
  int wm   = (w >> 1) * 32;
  int wn   = (w & 1) * 64;
  int lr   = lane & 15;
  int lg   = lane >> 4;

  f32x4 acc[2][4] = {};

  for (int kt = 0; kt < 2; kt++){
    // stage A: 64 rows x 64 k = 512 16B chunks, 2 per thread
    #pragma unroll
    for (int i=0;i<2;i++){
      int ci = tid + i*256;
      int row = ci >> 3, ch = ci & 7;
      *(uint4*)&Ah[row][ch*8] = *(const uint4*)(Ath + (size_t)(m0+row)*C_ + kt*BK + ch*8);
      *(uint4*)&Al[row][ch*8] = *(const uint4*)(Atl + (size_t)(m0+row)*C_ + kt*BK + ch*8);
    }
    // stage B: 128 rows x 64 k = 1024 16B chunks, 4 per thread
    #pragma unroll
    for (int i=0;i<4;i++){
      int ci = tid + i*256;
      int n = ci >> 3, ch = ci & 7;
      *(uint4*)&Bh[n][ch*8] = *(const uint4*)(Bth + (size_t)(n0+n)*C_ + kt*BK + ch*8);
      *(uint4*)&Bl[n][ch*8] = *(const uint4*)(Btl + (size_t)(n0+n)*C_ + kt*BK + ch*8);
    }
    __syncthreads();

    #pragma unroll
    for (int kh=0; kh<2; kh++){
      bf16x8 a_h[2], a_l[2];
      #pragma unroll
      for (int mt=0; mt<2; mt++){
        a_h[mt] = *(bf16x8*)&Ah[wm + mt*16 + lr][kh*32 + lg*8];
        a_l[mt] = *(bf16x8*)&Al[wm + mt*16 + lr][kh*32 + lg*8];
      }
      #pragma unroll
      for (int nt=0; nt<4; nt++){
        bf16x8 b_h = *(bf16x8*)&Bh[wn + nt*16 + lr][kh*32 + lg*8];
        bf16x8 b_l = *(bf16x8*)&Bl[wn + nt*16 + lr][kh*32 + lg*8];
        #pragma unroll
        for (int mt=0; mt<2; mt++){
          acc[mt][nt] = __builtin_amdgcn_mfma_f32_16x16x32_bf16(a_h[mt], b_h, acc[mt][nt], 0,0,0);
          acc[mt][nt] = __builtin_amdgcn_mfma_f32_16x16x32_bf16(a_l[mt], b_h, acc[mt][nt], 0,0,0);
          acc[mt][nt] = __builtin_amdgcn_mfma_f32_16x16x32_bf16(a_h[mt], b_l, acc[mt][nt], 0,0,0);
        }
      }
    }
    __syncthreads();
  }

  #pragma unroll
  for (int mt=0; mt<2; mt++)
    #pragma unroll
    for (int nt=0; nt<4; nt++)
      #pragma unroll
      for (int r=0; r<4; r++){
        int row = m0 + wm + mt*16 + lg*4 + r;
        int col = n0 + wn + nt*16 + lr;
        out[(size_t)row*V_ + col] = acc[mt][nt][r] * osc;
      }
}

// ---------------------------------------------------------------------------
extern "C" void kernel_launch(void* const* d_in, const int* in_sizes, int n_in,
                              void* d_out, int out_size, void* d_ws, size_t ws_size,
                              hipStream_t stream)
{
  const float* x     = (const float*)d_in[0];
  const float* basis = (const float*)d_in[1];
  const float* qc    = (const float*)d_in[2];
  const float* kc    = (const float*)d_in[3];
  const float* vc    = (const float*)d_in[4];
  const float* oc    = (const float*)d_in[5];
  const float* dptr  = (const float*)d_in[6];
  const float* sptr  = (const float*)d_in[7];
  float* out = (float*)d_out;
  float* ws  = (float*)d_ws;

  const size_t M = (size_t)B_*T_;
  // Workspace layout (offsets in FLOAT units; bf16 arrays use 2 elems/float):
  //   Woh  bf16 V*C      = 131072 bf16 ->  65536 f   @ 0
  //   Wol  bf16 V*C      = 131072 bf16 ->  65536 f   @ 65536
  //   Wth  bf16 3*C*V    = 393216 bf16 -> 196608 f   @ 131072
  //   Wtl  bf16 3*C*V    = 393216 bf16 -> 196608 f   @ 327680
  //   qkv  f32  3*M*C    = 6291456 f                 @ 524288
  //   reth bf16 M*C      = 2097152 bf16 -> 1048576 f @ 6815744
  //   retl bf16 M*C      = 2097152 bf16 -> 1048576 f @ 7864320
  //   kv   f32  B*NC*C*C = 8388608 f                 @ 8912896
  //   end = 17301504 f = 69.2 MB
  bf16_t* Woh = (bf16_t*)ws;
  bf16_t* Wol = Woh + (size_t)V_*C_;
  bf16_t* Wth = (bf16_t*)(ws + 131072);
  bf16_t* Wtl = Wth + 3*(size_t)C_*V_;
  float*  qkv = ws + 524288;
  bf16_t* reth = (bf16_t*)(ws + 6815744);
  bf16_t* retl = reth + M*C_;
  float*  kv  = ws + 8912896;

  float* q = qkv;
  float* k = qkv + M*C_;
  float* v = qkv + 2*M*C_;

  hipLaunchKernelGGL(weights_kernel, dim3(512), dim3(256), 0, stream,
                     basis, qc, kc, vc, oc, Woh, Wol, Wth, Wtl);
  hipLaunchKernelGGL(proj_mfma_kernel, dim3(256,3), dim3(256), 0, stream,
                     x, Wth, Wtl, qkv);
  hipLaunchKernelGGL(kvsum_kernel, dim3(NC_, B_), dim3(256), 0, stream, k, v, dptr, kv);
  hipLaunchKernelGGL(scan_kernel, dim3(512), dim3(256), 0, stream, kv, dptr);
  hipLaunchKernelGGL(intra_kernel, dim3(NC_, B_), dim3(256), 0, stream,
                     q, k, v, kv, dptr, reth, retl);
  hipLaunchKernelGGL(out_mfma_kernel, dim3(256, 8), dim3(256), 0, stream,
                     reth, retl, Woh, Wol, sptr, out);
}

// Round 5
// 279.447 us; speedup vs baseline: 2.1761x; 1.0424x over previous
//
#include <hip/hip_runtime.h>
#include <math.h>

// Problem constants
#define B_   8
#define T_   2048
#define V_   1024
#define C_   128
#define NB2  64     // 2*NB
#define L_   32     // chunk length for the linearized recurrence
#define NC_  64     // T_/L_

typedef _Float16 f16_t;
typedef f16_t f16x8 __attribute__((ext_vector_type(8)));
typedef float f32x4 __attribute__((ext_vector_type(4)));

__device__ __forceinline__ float sigmoidf_(float x){ return 1.0f/(1.0f+expf(-x)); }

// ---------------------------------------------------------------------------
// K0: weights. proj 0..2: softmax(basis@coeffs^T, axis=V) -> fp16,
//     TRANSPOSED (Wt[c][v]) for MFMA B-fragment reads.
//     proj 3: Wo (V,C) row-major fp16 (rows are B-fragments for out GEMM).
// fp16 is safe: softmax weights ~1e-3 >> 6.1e-5 min-normal; |logits| small.
// ---------------------------------------------------------------------------
__global__ __launch_bounds__(256) void weights_kernel(
    const float* __restrict__ basis,
    const float* __restrict__ qc, const float* __restrict__ kc,
    const float* __restrict__ vc, const float* __restrict__ oc,
    f16_t* __restrict__ Wo, f16_t* __restrict__ Wt)
{
  int blk  = blockIdx.x;
  int proj = blk >> 7;
  int c    = blk & 127;
  const float* coeffs = (proj==0)?qc : (proj==1)?kc : (proj==2)?vc : oc;

  __shared__ float coef[NB2];
  __shared__ float red[256];
  int tid = threadIdx.x;
  if (tid < NB2) coef[tid] = coeffs[c*NB2 + tid];
  __syncthreads();

  float l[4];
  for (int i=0;i<4;i++){
    int v = tid + i*256;
    const float4* bp = (const float4*)(basis + (size_t)v*NB2);
    float s = 0.f;
    #pragma unroll
    for (int f=0; f<NB2/4; f++){
      float4 b4 = bp[f];
      s += b4.x*coef[f*4+0] + b4.y*coef[f*4+1] + b4.z*coef[f*4+2] + b4.w*coef[f*4+3];
    }
    l[i] = s;
  }
  if (proj == 3){
    for (int i=0;i<4;i++){ int v = tid+i*256; Wo[(size_t)v*C_ + c] = (f16_t)l[i]; }
    return;
  }
  // softmax over V (1024 values per column c)
  float mx = fmaxf(fmaxf(l[0],l[1]), fmaxf(l[2],l[3]));
  red[tid] = mx; __syncthreads();
  for (int s=128; s>0; s>>=1){ if (tid<s) red[tid] = fmaxf(red[tid], red[tid+s]); __syncthreads(); }
  mx = red[0]; __syncthreads();
  float sum = 0.f;
  for (int i=0;i<4;i++) sum += expf(l[i]-mx);
  red[tid] = sum; __syncthreads();
  for (int s=128; s>0; s>>=1){ if (tid<s) red[tid] += red[tid+s]; __syncthreads(); }
  float inv = 1.0f/red[0];
  f16_t* tp = Wt + ((size_t)proj*C_ + c)*V_;
  for (int i=0;i<4;i++){
    int v = tid+i*256;
    tp[v] = (f16_t)(expf(l[i]-mx)*inv);
  }
}

// ---------------------------------------------------------------------------
// K1: q/k/v = x @ W, single-term fp16 MFMA (x cvt on the fly).
// 64x128 block tile, BK=64, 256 threads = 4 waves (2x2 of 32x64 wave tiles).
// LDS 27.6 KB -> 5 blocks/CU; grid 768 = 3 blocks/CU fully resident.
// ---------------------------------------------------------------------------
#define BM 64
#define BN 128
#define BK 64
#define PADK 72   // LDS row stride in f16 (144 B, 16B-aligned, breaks pow2 banks)

__global__ __launch_bounds__(256, 2) void proj_mfma_kernel(
    const float* __restrict__ x,
    const f16_t* __restrict__ Wt,
    float* __restrict__ out)
{
  const int M = B_*T_;
  int proj = blockIdx.y;
  int m0   = blockIdx.x * BM;
  float* op = out + (size_t)proj*M*C_;
  const f16_t* bp = Wt + (size_t)proj*C_*V_;

  __shared__ f16_t As[BM][PADK];
  __shared__ f16_t Bs[BN][PADK];

  int tid  = threadIdx.x;
  int lane = tid & 63;
  int w    = tid >> 6;
  int wm   = (w >> 1) * 32;
  int wn   = (w & 1) * 64;
  int lr   = lane & 15;
  int lg   = lane >> 4;

  f32x4 acc[2][4] = {};

  for (int kt = 0; kt < V_/BK; kt++){
    // stage A: 64x64 fp32 -> f16. 1024 float4 chunks, 4/thread.
    #pragma unroll
    for (int i=0;i<4;i++){
      int f4  = tid + i*256;
      int row = f4 >> 4, q = f4 & 15;
      float4 xv = *(const float4*)(x + (size_t)(m0+row)*V_ + kt*BK + q*4);
      union { f16_t h[4]; ushort4 u; } hh;
      hh.h[0]=(f16_t)xv.x; hh.h[1]=(f16_t)xv.y; hh.h[2]=(f16_t)xv.z; hh.h[3]=(f16_t)xv.w;
      *(ushort4*)&As[row][q*4] = hh.u;
    }
    // stage B: 128x64 f16 = 1024 16B chunks, 4/thread.
    #pragma unroll
    for (int i=0;i<4;i++){
      int ci = tid + i*256;
      int n = ci >> 3, ch = ci & 7;
      *(uint4*)&Bs[n][ch*8] = *(const uint4*)(bp + (size_t)n*V_ + kt*BK + ch*8);
    }
    __syncthreads();

    #pragma unroll
    for (int kh=0; kh<2; kh++){
      f16x8 a[2];
      #pragma unroll
      for (int mt=0; mt<2; mt++)
        a[mt] = *(f16x8*)&As[wm + mt*16 + lr][kh*32 + lg*8];
      #pragma unroll
      for (int nt=0; nt<4; nt++){
        f16x8 b = *(f16x8*)&Bs[wn + nt*16 + lr][kh*32 + lg*8];
        #pragma unroll
        for (int mt=0; mt<2; mt++)
          acc[mt][nt] = __builtin_amdgcn_mfma_f32_16x16x32_f16(a[mt], b, acc[mt][nt], 0,0,0);
      }
    }
    __syncthreads();
  }

  // epilogue: C/D layout col=lane&15, row=(lane>>4)*4+reg
  #pragma unroll
  for (int mt=0; mt<2; mt++)
    #pragma unroll
    for (int nt=0; nt<4; nt++)
      #pragma unroll
      for (int r=0; r<4; r++){
        int row = m0 + wm + mt*16 + lg*4 + r;
        int col = wn + nt*16 + lr;
        op[(size_t)row*C_ + col] = acc[mt][nt][r];
      }
}

// ---------------------------------------------------------------------------
// K2: per-chunk KV summary: kv[b][ci][c][dd] = sum_j d^{L-1-j} k_j[c] v_j[dd]
// ---------------------------------------------------------------------------
__global__ __launch_bounds__(256) void kvsum_kernel(
    const float* __restrict__ k, const float* __restrict__ v,
    const float* __restrict__ dptr, float* __restrict__ kv)
{
  int ci = blockIdx.x, b = blockIdx.y;
  float d = sigmoidf_(dptr[0]);
  __shared__ float ks[L_][132];
  __shared__ float vs[L_][132];
  int tid = threadIdx.x;
  const float* kp = k + ((size_t)b*T_ + ci*L_)*C_;
  const float* vp = v + ((size_t)b*T_ + ci*L_)*C_;
  #pragma unroll
  for (int i=0;i<4;i++){
    int idx = tid + i*256;
    int j = idx >> 5, c4 = idx & 31;
    float w = powf(d, (float)(L_-1-j));
    float4 k4 = *(const float4*)(kp + (size_t)j*C_ + c4*4);
    k4.x*=w; k4.y*=w; k4.z*=w; k4.w*=w;
    *(float4*)&ks[j][c4*4] = k4;
    *(float4*)&vs[j][c4*4] = *(const float4*)(vp + (size_t)j*C_ + c4*4);
  }
  __syncthreads();
  int tc = tid >> 4, td = tid & 15;
  float acc[8][8] = {};
  for (int j=0;j<L_;j++){
    float kr[8], vr[8];
    *(float4*)&kr[0] = *(float4*)&ks[j][tc*8];
    *(float4*)&kr[4] = *(float4*)&ks[j][tc*8+4];
    *(float4*)&vr[0] = *(float4*)&vs[j][td*8];
    *(float4*)&vr[4] = *(float4*)&vs[j][td*8+4];
    #pragma unroll
    for (int a=0;a<8;a++)
      #pragma unroll
      for (int bb=0;bb<8;bb++) acc[a][bb] += kr[a]*vr[bb];
  }
  float* op = kv + ((size_t)b*NC_ + ci)*C_*C_;
  for (int a=0;a<8;a++)
    for (int b4=0;b4<2;b4++)
      *(float4*)(op + (size_t)(tc*8+a)*C_ + td*8 + b4*4) =
        make_float4(acc[a][b4*4],acc[a][b4*4+1],acc[a][b4*4+2],acc[a][b4*4+3]);
}

// ---------------------------------------------------------------------------
// K3: in-place exclusive scan over chunks
// ---------------------------------------------------------------------------
__global__ __launch_bounds__(256) void scan_kernel(
    float* __restrict__ kv, const float* __restrict__ dptr)
{
  int idx = blockIdx.x*256 + threadIdx.x;
  int b = idx >> 14, e = idx & 16383;
  float d  = sigmoidf_(dptr[0]);
  float dL = powf(d, (float)L_);
  float* p = kv + (size_t)b*NC_*C_*C_ + e;
  float m = 0.f;
  for (int i=0;i<NC_;i++){
    float s = p[(size_t)i*C_*C_];
    p[(size_t)i*C_*C_] = m;
    m = dL*m + s;
  }
}

// ---------------------------------------------------------------------------
// K4: per-chunk retrieved; epilogue writes ret as fp16 (feeds out MFMA)
// ---------------------------------------------------------------------------
__global__ __launch_bounds__(256) void intra_kernel(
    const float* __restrict__ q, const float* __restrict__ k,
    const float* __restrict__ v, const float* __restrict__ Minit,
    const float* __restrict__ dptr,
    f16_t* __restrict__ ret)
{
  int ci = blockIdx.x, b = blockIdx.y;
  int tid = threadIdx.x;
  float d = sigmoidf_(dptr[0]);
  __shared__ float qs[L_][132];
  __shared__ float kvs[L_][132];
  __shared__ float ps[L_][33];
  __shared__ float dpow[L_+1];
  if (tid <= L_) dpow[tid] = powf(d, (float)tid);

  const float* qp = q + ((size_t)b*T_ + ci*L_)*C_;
  const float* kp = k + ((size_t)b*T_ + ci*L_)*C_;
  const float* vp = v + ((size_t)b*T_ + ci*L_)*C_;
  #pragma unroll
  for (int i=0;i<4;i++){
    int idx = tid + i*256;
    int j = idx >> 5, c4 = idx & 31;
    *(float4*)&qs[j][c4*4]  = *(const float4*)(qp + (size_t)j*C_ + c4*4);
    *(float4*)&kvs[j][c4*4] = *(const float4*)(kp + (size_t)j*C_ + c4*4);
  }
  __syncthreads();

  {
    int tr = tid >> 4, tj = tid & 15;
    float s[2][2] = {};
    for (int c4=0;c4<32;c4++){
      float4 q4[2], k4[2];
      #pragma unroll
      for (int i=0;i<2;i++) q4[i] = *(float4*)&qs[tr*2+i][c4*4];
      #pragma unroll
      for (int i=0;i<2;i++) k4[i] = *(float4*)&kvs[tj*2+i][c4*4];
      #pragma unroll
      for (int a=0;a<2;a++)
        #pragma unroll
        for (int bb=0;bb<2;bb++)
          s[a][bb] += q4[a].x*k4[bb].x + q4[a].y*k4[bb].y + q4[a].z*k4[bb].z + q4[a].w*k4[bb].w;
    }
    #pragma unroll
    for (int a=0;a<2;a++)
      #pragma unroll
      for (int bb=0;bb<2;bb++){
        int r = tr*2+a, j = tj*2+bb;
        ps[r][j] = (j < r) ? s[a][bb]*dpow[r-1-j] : 0.f;
      }
  }
  __syncthreads();
  #pragma unroll
  for (int i=0;i<4;i++){
    int idx = tid + i*256;
    int j = idx >> 5, c4 = idx & 31;
    *(float4*)&kvs[j][c4*4] = *(const float4*)(vp + (size_t)j*C_ + c4*4);
  }
  __syncthreads();

  int tx = tid & 31, ty = tid >> 5;
  float acc[4][4] = {};
  const float* Mp = Minit + ((size_t)b*NC_ + ci)*C_*C_;
  for (int c=0;c<C_;c++){
    float4 m4 = *(const float4*)(Mp + (size_t)c*C_ + tx*4);
    #pragma unroll
    for (int r=0;r<4;r++){
      float qv = qs[ty*4+r][c];
      acc[r][0] += qv*m4.x; acc[r][1] += qv*m4.y; acc[r][2] += qv*m4.z; acc[r][3] += qv*m4.w;
    }
  }
  #pragma unroll
  for (int r=0;r<4;r++){
    float sc = dpow[ty*4+r];
    #pragma unroll
    for (int j=0;j<4;j++) acc[r][j] *= sc;
  }
  for (int j=0;j<L_;j++){
    float4 v4 = *(float4*)&kvs[j][tx*4];
    #pragma unroll
    for (int r=0;r<4;r++){
      float p = ps[ty*4+r][j];
      acc[r][0] += p*v4.x; acc[r][1] += p*v4.y; acc[r][2] += p*v4.z; acc[r][3] += p*v4.w;
    }
  }
  size_t rbase = ((size_t)b*T_ + ci*L_)*C_;
  for (int r=0;r<4;r++){
    union { f16_t h[4]; ushort4 u; } hh;
    #pragma unroll
    for (int j=0;j<4;j++) hh.h[j] = (f16_t)acc[r][j];
    *(ushort4*)(ret + rbase + (size_t)(ty*4+r)*C_ + tx*4) = hh.u;
  }
}

// ---------------------------------------------------------------------------
// K5: out = (ret @ Wo^T) * out_scale, single-term fp16 MFMA.
// M=16384, N=1024, K=128. BM=64, BN=128, kt loop 2x BK=64. grid (256,8).
// ---------------------------------------------------------------------------
__global__ __launch_bounds__(256, 2) void out_mfma_kernel(
    const f16_t* __restrict__ A, const f16_t* __restrict__ Bw,
    const float* __restrict__ scl, float* __restrict__ out)
{
  int m0 = blockIdx.x * BM;
  int n0 = blockIdx.y * BN;
  float osc = scl[0];

  __shared__ f16_t As[BM][PADK];
  __shared__ f16_t Bs[BN][PADK];

  int tid  = threadIdx.x;
  int lane = tid & 63;
  int w    = tid >> 6;
  int wm   = (w >> 1) * 32;
  int wn   = (w & 1) * 64;
  int lr   = lane & 15;
  int lg   = lane >> 4;

  f32x4 acc[2][4] = {};

  for (int kt = 0; kt < 2; kt++){
    // stage A: 64x64 f16 = 512 16B chunks, 2/thread
    #pragma unroll
    for (int i=0;i<2;i++){
      int ci = tid + i*256;
      int row = ci >> 3, ch = ci & 7;
      *(uint4*)&As[row][ch*8] = *(const uint4*)(A + (size_t)(m0+row)*C_ + kt*BK + ch*8);
    }
    // stage B: 128x64 f16 = 1024 16B chunks, 4/thread
    #pragma unroll
    for (int i=0;i<4;i++){
      int ci = tid + i*256;
      int n = ci >> 3, ch = ci & 7;
      *(uint4*)&Bs[n][ch*8] = *(const uint4*)(Bw + (size_t)(n0+n)*C_ + kt*BK + ch*8);
    }
    __syncthreads();

    #pragma unroll
    for (int kh=0; kh<2; kh++){
      f16x8 a[2];
      #pragma unroll
      for (int mt=0; mt<2; mt++)
        a[mt] = *(f16x8*)&As[wm + mt*16 + lr][kh*32 + lg*8];
      #pragma unroll
      for (int nt=0; nt<4; nt++){
        f16x8 b = *(f16x8*)&Bs[wn + nt*16 + lr][kh*32 + lg*8];
        #pragma unroll
        for (int mt=0; mt<2; mt++)
          acc[mt][nt] = __builtin_amdgcn_mfma_f32_16x16x32_f16(a[mt], b, acc[mt][nt], 0,0,0);
      }
    }
    __syncthreads();
  }

  #pragma unroll
  for (int mt=0; mt<2; mt++)
    #pragma unroll
    for (int nt=0; nt<4; nt++)
      #pragma unroll
      for (int r=0; r<4; r++){
        int row = m0 + wm + mt*16 + lg*4 + r;
        int col = n0 + wn + nt*16 + lr;
        out[(size_t)row*V_ + col] = acc[mt][nt][r] * osc;
      }
}

// ---------------------------------------------------------------------------
extern "C" void kernel_launch(void* const* d_in, const int* in_sizes, int n_in,
                              void* d_out, int out_size, void* d_ws, size_t ws_size,
                              hipStream_t stream)
{
  const float* x     = (const float*)d_in[0];
  const float* basis = (const float*)d_in[1];
  const float* qc    = (const float*)d_in[2];
  const float* kc    = (const float*)d_in[3];
  const float* vc    = (const float*)d_in[4];
  const float* oc    = (const float*)d_in[5];
  const float* dptr  = (const float*)d_in[6];
  const float* sptr  = (const float*)d_in[7];
  float* out = (float*)d_out;
  float* ws  = (float*)d_ws;

  const size_t M = (size_t)B_*T_;
  // Workspace layout (offsets in FLOAT units; f16 arrays use 2 elems/float):
  //   Wo   f16 V*C      = 131072 h ->  65536 f   @ 0
  //   Wt   f16 3*C*V    = 393216 h -> 196608 f   @ 65536
  //   qkv  f32 3*M*C    = 6291456 f              @ 262144
  //   ret  f16 M*C      = 2097152 h -> 1048576 f @ 6553600
  //   kv   f32 B*NC*C*C = 8388608 f              @ 7602176
  //   end = 15990784 f = 64.0 MB
  f16_t* Wo  = (f16_t*)ws;
  f16_t* Wt  = (f16_t*)(ws + 65536);
  float* qkv = ws + 262144;
  f16_t* ret = (f16_t*)(ws + 6553600);
  float* kv  = ws + 7602176;

  float* q = qkv;
  float* k = qkv + M*C_;
  float* v = qkv + 2*M*C_;

  hipLaunchKernelGGL(weights_kernel, dim3(512), dim3(256), 0, stream,
                     basis, qc, kc, vc, oc, Wo, Wt);
  hipLaunchKernelGGL(proj_mfma_kernel, dim3(256,3), dim3(256), 0, stream,
                     x, Wt, qkv);
  hipLaunchKernelGGL(kvsum_kernel, dim3(NC_, B_), dim3(256), 0, stream, k, v, dptr, kv);
  hipLaunchKernelGGL(scan_kernel, dim3(512), dim3(256), 0, stream, kv, dptr);
  hipLaunchKernelGGL(intra_kernel, dim3(NC_, B_), dim3(256), 0, stream,
                     q, k, v, kv, dptr, ret);
  hipLaunchKernelGGL(out_mfma_kernel, dim3(256, 8), dim3(256), 0, stream,
                     ret, Wo, sptr, out);
}